// Round 8
// baseline (124.843 us; speedup 1.0000x reference)
//
#include <hip/hip_runtime.h>
#include <cstdint>

static constexpr int B    = 16;
static constexpr int P    = 22536;
static constexpr int NOBJ = 32;
static constexpr int CHUNKS = (P + 255) / 256;   // 89
static constexpr int NBLK   = CHUNKS * B;        // 1424
static constexpr int BP   = B * P;

// ---------------------------------------------------------------- K1: per-object argmax over priors
// One block per (image, object). Packed (iou_bits<<32)|~prior: u64 max =>
// max iou, ties prefer smallest prior (first-occurrence, like jnp.argmax).
__global__ __launch_bounds__(256) void k_objbest(
    const float4* __restrict__ boxes, const float4* __restrict__ priors,
    unsigned long long* __restrict__ objbest) {
  const int b = blockIdx.x >> 5;          // / NOBJ
  const int o = blockIdx.x & (NOBJ - 1);
  float4 bx = boxes[b * NOBJ + o];
  float barea = (bx.z - bx.x) * (bx.w - bx.y);   // same op order as reference
  unsigned long long best = 0ull;
  for (int p = threadIdx.x; p < P; p += 256) {
    float4 pc = priors[p];
    float hx = pc.z * 0.5f, hy = pc.w * 0.5f;    // c/2. == c*0.5f exactly
    float px0 = pc.x - hx, py0 = pc.y - hy;
    float px1 = pc.x + hx, py1 = pc.y + hy;
    float parea = (px1 - px0) * (py1 - py0);
    float lx = fmaxf(bx.x, px0), ly = fmaxf(bx.y, py0);
    float rx = fminf(bx.z, px1), ry = fminf(bx.w, py1);
    float w = fmaxf(rx - lx, 0.f), h = fmaxf(ry - ly, 0.f);
    float inter = w * h;
    float iou = inter / (barea + parea - inter); // IEEE div, matches reference bits
    unsigned long long pk =
        ((unsigned long long)__float_as_uint(iou) << 32) |
        (unsigned long long)(unsigned)(~(unsigned)p);
    best = (pk > best) ? pk : best;
  }
  for (int off = 32; off > 0; off >>= 1) {
    unsigned long long other = __shfl_down(best, off, 64);
    best = (other > best) ? other : best;
  }
  __shared__ unsigned long long sb[4];
  int lane = threadIdx.x & 63, wid = threadIdx.x >> 6;
  if (lane == 0) sb[wid] = best;
  __syncthreads();
  if (threadIdx.x == 0) {
    unsigned long long r = sb[0];
    r = (sb[1] > r) ? sb[1] : r;
    r = (sb[2] > r) ? sb[2] : r;
    r = (sb[3] > r) ? sb[3] : r;
    objbest[blockIdx.x] = r;
  }
}

// ---------------------------------------------------------------- K2: match + force + classloc
// Grid (CHUNKS, B). Writes tclass[]; per-block partials (no atomics).
__global__ __launch_bounds__(256) void k_prep(
    const float4* __restrict__ plocs, const float4* __restrict__ boxes,
    const int* __restrict__ labels, const float4* __restrict__ priors,
    const unsigned long long* __restrict__ objbest,
    int* __restrict__ tclass, float* __restrict__ partS, int* __restrict__ partN) {
  const int b    = blockIdx.y;
  const int base = blockIdx.x * 256;
  const int tid  = threadIdx.x;
  const int p    = base + tid;

  __shared__ float4 sbox[NOBJ];
  __shared__ float  sarea[NOBJ];
  __shared__ int    slab[NOBJ];
  __shared__ int    sfp[NOBJ];   // forced prior index (-1 if invalid)
  __shared__ int    sfc[NOBJ];   // filtered object index (cumsum(valid)-1)

  if (tid < NOBJ) {
    float4 bx = boxes[b * NOBJ + tid];
    sbox[tid]  = bx;
    sarea[tid] = (bx.z - bx.x) * (bx.w - bx.y);
    slab[tid]  = labels[b * NOBJ + tid];
    unsigned long long pk = objbest[b * NOBJ + tid];
    float iou  = __uint_as_float((unsigned)(pk >> 32));
    bool valid = iou > 0.f;
    unsigned long long m = __ballot(valid);       // lanes 32..63 inactive -> 0
    sfp[tid] = valid ? (int)(~(unsigned)(pk & 0xFFFFFFFFull)) : -1;
    sfc[tid] = (int)__popcll(m & ((1ull << tid) - 1ull));
  }
  __syncthreads();

  float mySl1 = 0.f; int myPos = 0; int lab = -1;
  if (p < P) {
    float4 pc = priors[p];
    float hx = pc.z * 0.5f, hy = pc.w * 0.5f;
    float px0 = pc.x - hx, py0 = pc.y - hy;
    float px1 = pc.x + hx, py1 = pc.y + hy;
    float parea = (px1 - px0) * (py1 - py0);
    float ov = -1.f; int obj = 0;
    #pragma unroll 8
    for (int o = 0; o < NOBJ; ++o) {
      float4 bx = sbox[o];
      float lx = fmaxf(bx.x, px0), ly = fmaxf(bx.y, py0);
      float rx = fminf(bx.z, px1), ry = fminf(bx.w, py1);
      float w = fmaxf(rx - lx, 0.f), h = fmaxf(ry - ly, 0.f);
      float inter = w * h;
      float iou = inter / (sarea[o] + parea - inter);
      if (iou > ov) { ov = iou; obj = o; }       // strict >: first max wins
    }
    #pragma unroll
    for (int j = 0; j < NOBJ; ++j) {             // ascending j: last writer wins
      if (sfp[j] == p) { ov = 1.0f; obj = sfc[j]; }
    }
    if (ov < 0.4f)      lab = 0;                 // fp32(0.5-0.1) == 0.4f
    else if (ov < 0.5f) lab = -1;
    else                lab = slab[obj];
    tclass[b * P + p] = lab;
    if (lab > 0) {
      myPos = 1;
      float4 bx = sbox[obj];                     // quirky filtered index, like ref
      float cx = (bx.x + bx.z) * 0.5f;
      float cy = (bx.y + bx.w) * 0.5f;
      float cw = bx.z - bx.x;
      float ch = bx.w - bx.y;
      float gx = (cx - pc.x) / (pc.z / 10.f);    // keep the /10. division
      float gy = (cy - pc.y) / (pc.w / 10.f);
      float gw = logf(cw / pc.z) * 5.f;
      float gh = logf(ch / pc.w) * 5.f;
      float4 pl = plocs[(size_t)b * P + p];
      float d, a;
      d = pl.x - gx; a = fabsf(d); mySl1 += (a < 1.f) ? 0.5f * d * d : a - 0.5f;
      d = pl.y - gy; a = fabsf(d); mySl1 += (a < 1.f) ? 0.5f * d * d : a - 0.5f;
      d = pl.z - gw; a = fabsf(d); mySl1 += (a < 1.f) ? 0.5f * d * d : a - 0.5f;
      d = pl.w - gh; a = fabsf(d); mySl1 += (a < 1.f) ? 0.5f * d * d : a - 0.5f;
    }
  }
  for (int off = 32; off > 0; off >>= 1) {
    mySl1 += __shfl_down(mySl1, off, 64);
    myPos += __shfl_down(myPos, off, 64);
  }
  __shared__ float sv[4];
  __shared__ int   sc[4];
  int lane = tid & 63, wid = tid >> 6;
  if (lane == 0) { sv[wid] = mySl1; sc[wid] = myPos; }
  __syncthreads();
  if (tid == 0) {
    partS[b * CHUNKS + blockIdx.x] = sv[0] + sv[1] + sv[2] + sv[3];
    partN[b * CHUNKS + blockIdx.x] = sc[0] + sc[1] + sc[2] + sc[3];
  }
}

// Focal-loss contribution of one float4 (4 classes) given target t and the
// 1-indexed class kb of element .x. Neg path applied to all 4 with weight w
// (0 masks ignore); rare positive class gets a correction.
// loss_neg = 0.75*p^2*(x+log u); loss_pos = 0.25*(1-p)^2*log u; u=1+e^-x, p=1/u.
__device__ __forceinline__ void focal4(float4 s, int t, int kb, float& acc) {
  float w = (t >= 0) ? 0.75f : 0.f;
  float xs[4] = {s.x, s.y, s.z, s.w};
  float accl = 0.f;
  #pragma unroll
  for (int q = 0; q < 4; ++q) {
    float x  = xs[q];
    float e  = __expf(-x);
    float u  = 1.f + e;
    float r  = __builtin_amdgcn_rcpf(u);
    float lu = __logf(u);
    accl += (x + lu) * (r * r);
  }
  acc += w * accl;
  unsigned d = (unsigned)(t - kb);         // t==kb+d with d<4 iff positive here
  if (d < 4u) {
    float x  = (d < 2u) ? ((d == 0u) ? s.x : s.y)
                        : ((d == 2u) ? s.z : s.w);
    float e  = __expf(-x);
    float u  = 1.f + e;
    float r  = __builtin_amdgcn_rcpf(u);
    float lu = __logf(u);
    float omp = e * r;                     // 1-p
    acc += 0.25f * omp * omp * lu - 0.75f * (x + lu) * (r * r);
  }
}

// ---------------------------------------------------------------- K3: focal
// Grid (CHUNKS, B): one 256-prior chunk per block. tclass staged to LDS once;
// 2 batches of 10 unconditional coalesced float4 loads.
__global__ __launch_bounds__(256, 4) void k_focal(
    const float4* __restrict__ scores, const int* __restrict__ tclass,
    float* __restrict__ partF) {
  const int b    = blockIdx.y;
  const int base = blockIdx.x * 256;
  const int tid  = threadIdx.x;
  __shared__ int scls[256];
  const int nval = (P - base < 256) ? (P - base) : 256;
  if (tid < nval) scls[tid] = tclass[b * P + base + tid];   // coalesced
  __syncthreads();

  float acc = 0.f;
  const float4* srow = scores + ((size_t)b * P + base) * 20;
  if (nval == 256) {                       // full chunk: 5120 float4, unguarded
    #pragma unroll
    for (int bt = 0; bt < 2; ++bt) {
      float4 s[10];
      const int i0 = tid + bt * 2560;
      #pragma unroll
      for (int j = 0; j < 10; ++j) s[j] = srow[i0 + j * 256];  // 10 in flight
      #pragma unroll
      for (int j = 0; j < 10; ++j) {
        const int idx = i0 + j * 256;
        const int pl  = idx / 20;
        focal4(s[j], scls[pl], (idx - pl * 20) * 4 + 1, acc);
      }
    }
  } else {                                 // tail chunk (1 per image)
    const int lim = nval * 20;
    for (int idx = tid; idx < lim; idx += 256) {
      float4 sv = srow[idx];
      const int pl = idx / 20;
      focal4(sv, scls[pl], (idx - pl * 20) * 4 + 1, acc);
    }
  }

  for (int off = 32; off > 0; off >>= 1) acc += __shfl_down(acc, off, 64);
  __shared__ float sv[4];
  int lane = tid & 63, wid = tid >> 6;
  if (lane == 0) sv[wid] = acc;
  __syncthreads();
  if (tid == 0) partF[b * CHUNKS + blockIdx.x] = sv[0] + sv[1] + sv[2] + sv[3];
}

// ---------------------------------------------------------------- K4: final reduce
__global__ __launch_bounds__(256) void k_final(
    const float* __restrict__ partF, const float* __restrict__ partS,
    const int* __restrict__ partN, float* __restrict__ out) {
  const int tid = threadIdx.x;
  float sF = 0.f, sS = 0.f; int sN = 0;
  for (int i = tid; i < NBLK; i += 256) {
    sF += partF[i]; sS += partS[i]; sN += partN[i];
  }
  for (int off = 32; off > 0; off >>= 1) {
    sF += __shfl_down(sF, off, 64);
    sS += __shfl_down(sS, off, 64);
    sN += __shfl_down(sN, off, 64);
  }
  __shared__ float vF[4], vS[4];
  __shared__ int   vN[4];
  int lane = tid & 63, wid = tid >> 6;
  if (lane == 0) { vF[wid] = sF; vS[wid] = sS; vN[wid] = sN; }
  __syncthreads();
  if (tid == 0) {
    float f = vF[0] + vF[1] + vF[2] + vF[3];
    float s = vS[0] + vS[1] + vS[2] + vS[3];
    int   n = vN[0] + vN[1] + vN[2] + vN[3];
    float np = (float)(n >= 1 ? n : 1);
    out[0] = f / np + s / (np * 4.f);
  }
}

// ---------------------------------------------------------------- launch
// DIAGNOSTIC ROUND: two extra k_focal dispatches write to scratch partF2/partF3
// that k_final never reads -> output bit-identical to R7, and
// (dur_R8 - dur_R7)/2 = steady-state cost of one focal pass.
extern "C" void kernel_launch(void* const* d_in, const int* in_sizes, int n_in,
                              void* d_out, int out_size, void* d_ws, size_t ws_size,
                              hipStream_t stream) {
  const float* plocs   = (const float*)d_in[0];   // [B,P,4]
  const float* pscores = (const float*)d_in[1];   // [B,P,80]
  const float* boxes   = (const float*)d_in[2];   // [B,32,4]
  const int*   labels  = (const int*)d_in[3];     // [B,32]
  const float* priors  = (const float*)d_in[4];   // [P,4]
  float* out = (float*)d_out;

  char* w = (char*)d_ws;
  unsigned long long* objbest = (unsigned long long*)w;  // 512 u64    @0
  float* partF  = (float*)(w + 4096);                    // NBLK floats
  float* partS  = (float*)(w + 16384);                   // NBLK floats
  int*   partN  = (int*)(w + 28672);                     // NBLK ints
  float* partF2 = (float*)(w + 40960);                   // NBLK floats (probe)
  float* partF3 = (float*)(w + 53248);                   // NBLK floats (probe)
  int*   tcls   = (int*)(w + 65536);                     // BP ints

  k_objbest<<<B * NOBJ, 256, 0, stream>>>(
      (const float4*)boxes, (const float4*)priors, objbest);
  dim3 g(CHUNKS, B);
  k_prep<<<g, 256, 0, stream>>>(
      (const float4*)plocs, (const float4*)boxes, labels, (const float4*)priors,
      objbest, tcls, partS, partN);
  k_focal<<<g, 256, 0, stream>>>((const float4*)pscores, tcls, partF);
  k_focal<<<g, 256, 0, stream>>>((const float4*)pscores, tcls, partF2);  // probe
  k_focal<<<g, 256, 0, stream>>>((const float4*)pscores, tcls, partF3);  // probe
  k_final<<<1, 256, 0, stream>>>(partF, partS, partN, out);
}

// Round 9
// 66.229 us; speedup vs baseline: 1.8850x; 1.8850x over previous
//
#include <hip/hip_runtime.h>
#include <cstdint>

static constexpr int B    = 16;
static constexpr int P    = 22536;
static constexpr int NOBJ = 32;
static constexpr int NCLS = 80;
static constexpr int CHUNKS = (P + 255) / 256;   // 89
static constexpr int NBLK   = CHUNKS * B;        // 1424 bulk blocks
static constexpr int OBJB   = B * NOBJ;          // 512 objbest blocks
static constexpr int BP     = B * P;

// neg-path focal term: 0.75 * p^2 * (x + log u) with u=1+e^-x, p=1/u  (0.75 applied later)
__device__ __forceinline__ float negterm(float x) {
  float e  = __expf(-x);
  float u  = 1.f + e;
  float r  = __builtin_amdgcn_rcpf(u);
  float lu = __logf(u);
  return (x + lu) * (r * r);
}

// ---------------------------------------------------------------- Node 1: bulk focal + rowsums + objbest
// Blocks [0,NBLK): label-independent bulk focal over the block's 256-prior
// score slab. Quarter-prior layout: thread (pr<<2)|q owns 5 consecutive float4
// (20 elems) of prior pr's 80-class row -> lane stride 80B, 5KB/wave through L1
// (100% line utilization), per-prior rowsum via 2 shfl_xor in the 4-lane group.
// Blocks [NBLK,NBLK+OBJB): per-object argmax over priors (VALU work overlapped
// with bulk's memory stalls). Packed (iou_bits<<32)|~prior, IEEE div kept for
// bitwise-identical ordering vs the reference.
__global__ __launch_bounds__(256, 4) void k_bulk(
    const float4* __restrict__ scores, const float4* __restrict__ boxes,
    const float4* __restrict__ priors,
    float* __restrict__ rowsumS, float* __restrict__ partB,
    unsigned long long* __restrict__ objbest) {
  const int bid = blockIdx.x;
  const int tid = threadIdx.x;
  if (bid < NBLK) {
    const int b    = bid / CHUNKS;
    const int base = (bid - b * CHUNKS) * 256;
    const int nval = (P - base < 256) ? (P - base) : 256;
    const float4* srow = scores + ((size_t)b * P + base) * 20;
    const int q  = tid & 3;          // quarter within prior
    const int pr = tid >> 2;         // prior within 64-prior pass
    float acc = 0.f;
    if (nval == 256) {
      #pragma unroll
      for (int pass = 0; pass < 4; ++pass) {
        const int pl = pass * 64 + pr;
        const float4* qp = srow + pl * 20 + q * 5;
        float4 s[5];
        #pragma unroll
        for (int j = 0; j < 5; ++j) s[j] = qp[j];        // 5 loads in flight
        float rs = 0.f;
        #pragma unroll
        for (int j = 0; j < 5; ++j)
          rs += negterm(s[j].x) + negterm(s[j].y) + negterm(s[j].z) + negterm(s[j].w);
        acc += rs;                                       // pre-reduce: counted once
        rs += __shfl_xor(rs, 1, 64);
        rs += __shfl_xor(rs, 2, 64);
        if (q == 0) rowsumS[(size_t)b * P + base + pl] = 0.75f * rs;
      }
    } else {                                             // tail chunk (8 priors)
      for (int pass = 0; pass < 4; ++pass) {
        const int pl = pass * 64 + pr;
        if (pl < nval) {
          const float4* qp = srow + pl * 20 + q * 5;
          float rs = 0.f;
          for (int j = 0; j < 5; ++j) {
            float4 s = qp[j];
            rs += negterm(s.x) + negterm(s.y) + negterm(s.z) + negterm(s.w);
          }
          acc += rs;
          rs += __shfl_xor(rs, 1, 64);
          rs += __shfl_xor(rs, 2, 64);
          if (q == 0) rowsumS[(size_t)b * P + base + pl] = 0.75f * rs;
        }
      }
    }
    acc *= 0.75f;
    for (int off = 32; off > 0; off >>= 1) acc += __shfl_down(acc, off, 64);
    __shared__ float sv[4];
    int lane = tid & 63, wid = tid >> 6;
    if (lane == 0) sv[wid] = acc;
    __syncthreads();
    if (tid == 0) partB[bid] = sv[0] + sv[1] + sv[2] + sv[3];
  } else {
    // -------- objbest role
    const int bid2 = bid - NBLK;
    const int b = bid2 >> 5;
    const int o = bid2 & (NOBJ - 1);
    float4 bx = boxes[b * NOBJ + o];
    float barea = (bx.z - bx.x) * (bx.w - bx.y);   // same op order as reference
    unsigned long long best = 0ull;
    for (int p = tid; p < P; p += 256) {
      float4 pc = priors[p];
      float hx = pc.z * 0.5f, hy = pc.w * 0.5f;    // c/2. == c*0.5f exactly
      float px0 = pc.x - hx, py0 = pc.y - hy;
      float px1 = pc.x + hx, py1 = pc.y + hy;
      float parea = (px1 - px0) * (py1 - py0);
      float lx = fmaxf(bx.x, px0), ly = fmaxf(bx.y, py0);
      float rx = fminf(bx.z, px1), ry = fminf(bx.w, py1);
      float w = fmaxf(rx - lx, 0.f), h = fmaxf(ry - ly, 0.f);
      float inter = w * h;
      float iou = inter / (barea + parea - inter); // IEEE div: reference bits
      unsigned long long pk =
          ((unsigned long long)__float_as_uint(iou) << 32) |
          (unsigned long long)(unsigned)(~(unsigned)p);
      best = (pk > best) ? pk : best;
    }
    for (int off = 32; off > 0; off >>= 1) {
      unsigned long long other = __shfl_down(best, off, 64);
      best = (other > best) ? other : best;
    }
    __shared__ unsigned long long sb[4];
    int lane = tid & 63, wid = tid >> 6;
    if (lane == 0) sb[wid] = best;
    __syncthreads();
    if (tid == 0) {
      unsigned long long r = sb[0];
      r = (sb[1] > r) ? sb[1] : r;
      r = (sb[2] > r) ? sb[2] : r;
      r = (sb[3] > r) ? sb[3] : r;
      objbest[bid2] = r;
    }
  }
}

// ---------------------------------------------------------------- Node 2: match + force + classloc + focal corrections
// Grid (CHUNKS, B). Same matching semantics as before (forced-list ballot
// prefix = cumsum(valid)-1 quirk, ascending-j overwrite = last-writer-wins).
// Instead of writing tclass: ignore priors subtract their rowsum; positive
// priors gather one score element and swap its neg term for the pos term.
__global__ __launch_bounds__(256) void k_prep(
    const float4* __restrict__ plocs, const float* __restrict__ scoresF,
    const float4* __restrict__ boxes, const int* __restrict__ labels,
    const float4* __restrict__ priors,
    const unsigned long long* __restrict__ objbest,
    const float* __restrict__ rowsumS,
    float* __restrict__ partS, int* __restrict__ partN,
    float* __restrict__ partC) {
  const int b    = blockIdx.y;
  const int base = blockIdx.x * 256;
  const int tid  = threadIdx.x;
  const int p    = base + tid;

  __shared__ float4 sbox[NOBJ];
  __shared__ float  sarea[NOBJ];
  __shared__ int    slab[NOBJ];
  __shared__ int    sfp[NOBJ];   // forced prior index (-1 if invalid)
  __shared__ int    sfc[NOBJ];   // filtered object index (cumsum(valid)-1)

  if (tid < NOBJ) {
    float4 bx = boxes[b * NOBJ + tid];
    sbox[tid]  = bx;
    sarea[tid] = (bx.z - bx.x) * (bx.w - bx.y);
    slab[tid]  = labels[b * NOBJ + tid];
    unsigned long long pk = objbest[b * NOBJ + tid];
    float iou  = __uint_as_float((unsigned)(pk >> 32));
    bool valid = iou > 0.f;
    unsigned long long m = __ballot(valid);       // lanes 32..63 inactive -> 0
    sfp[tid] = valid ? (int)(~(unsigned)(pk & 0xFFFFFFFFull)) : -1;
    sfc[tid] = (int)__popcll(m & ((1ull << tid) - 1ull));
  }
  __syncthreads();

  float mySl1 = 0.f, myCorr = 0.f; int myPos = 0;
  if (p < P) {
    float4 pc = priors[p];
    float hx = pc.z * 0.5f, hy = pc.w * 0.5f;
    float px0 = pc.x - hx, py0 = pc.y - hy;
    float px1 = pc.x + hx, py1 = pc.y + hy;
    float parea = (px1 - px0) * (py1 - py0);
    float ov = -1.f; int obj = 0;
    #pragma unroll 8
    for (int o = 0; o < NOBJ; ++o) {
      float4 bx = sbox[o];
      float lx = fmaxf(bx.x, px0), ly = fmaxf(bx.y, py0);
      float rx = fminf(bx.z, px1), ry = fminf(bx.w, py1);
      float w = fmaxf(rx - lx, 0.f), h = fmaxf(ry - ly, 0.f);
      float inter = w * h;
      float iou = inter / (sarea[o] + parea - inter);
      if (iou > ov) { ov = iou; obj = o; }       // strict >: first max wins
    }
    #pragma unroll
    for (int j = 0; j < NOBJ; ++j) {             // ascending j: last writer wins
      if (sfp[j] == p) { ov = 1.0f; obj = sfc[j]; }
    }
    int lab;
    if (ov < 0.4f)      lab = 0;                 // fp32(0.5-0.1) == 0.4f
    else if (ov < 0.5f) lab = -1;
    else                lab = slab[obj];
    if (lab < 0) {
      myCorr -= rowsumS[(size_t)b * P + p];      // remove ignored prior's bulk
    } else if (lab > 0) {
      myPos = 1;
      float4 bx = sbox[obj];                     // quirky filtered index, like ref
      float cx = (bx.x + bx.z) * 0.5f;
      float cy = (bx.y + bx.w) * 0.5f;
      float cw = bx.z - bx.x;
      float ch = bx.w - bx.y;
      float gx = (cx - pc.x) / (pc.z / 10.f);    // keep the /10. division
      float gy = (cy - pc.y) / (pc.w / 10.f);
      float gw = logf(cw / pc.z) * 5.f;
      float gh = logf(ch / pc.w) * 5.f;
      float4 pl = plocs[(size_t)b * P + p];
      float d, a;
      d = pl.x - gx; a = fabsf(d); mySl1 += (a < 1.f) ? 0.5f * d * d : a - 0.5f;
      d = pl.y - gy; a = fabsf(d); mySl1 += (a < 1.f) ? 0.5f * d * d : a - 0.5f;
      d = pl.z - gw; a = fabsf(d); mySl1 += (a < 1.f) ? 0.5f * d * d : a - 0.5f;
      d = pl.w - gh; a = fabsf(d); mySl1 += (a < 1.f) ? 0.5f * d * d : a - 0.5f;
      // swap the positive class's neg term for the pos term
      float x  = scoresF[((size_t)b * P + p) * NCLS + (lab - 1)];
      float e  = __expf(-x);
      float u  = 1.f + e;
      float r  = __builtin_amdgcn_rcpf(u);
      float lu = __logf(u);
      float omp = e * r;                         // 1-p
      myCorr += 0.25f * omp * omp * lu - 0.75f * (x + lu) * (r * r);
    }
  }
  for (int off = 32; off > 0; off >>= 1) {
    mySl1  += __shfl_down(mySl1,  off, 64);
    myCorr += __shfl_down(myCorr, off, 64);
    myPos  += __shfl_down(myPos,  off, 64);
  }
  __shared__ float sv[4], sc2[4];
  __shared__ int   sc[4];
  int lane = tid & 63, wid = tid >> 6;
  if (lane == 0) { sv[wid] = mySl1; sc2[wid] = myCorr; sc[wid] = myPos; }
  __syncthreads();
  if (tid == 0) {
    const int bid = b * CHUNKS + blockIdx.x;
    partS[bid] = sv[0] + sv[1] + sv[2] + sv[3];
    partC[bid] = sc2[0] + sc2[1] + sc2[2] + sc2[3];
    partN[bid] = sc[0] + sc[1] + sc[2] + sc[3];
  }
}

// ---------------------------------------------------------------- Node 3: final reduce
__global__ __launch_bounds__(256) void k_final(
    const float* __restrict__ partB, const float* __restrict__ partC,
    const float* __restrict__ partS, const int* __restrict__ partN,
    float* __restrict__ out) {
  const int tid = threadIdx.x;
  float sF = 0.f, sS = 0.f; int sN = 0;
  for (int i = tid; i < NBLK; i += 256) {
    sF += partB[i] + partC[i];
    sS += partS[i];
    sN += partN[i];
  }
  for (int off = 32; off > 0; off >>= 1) {
    sF += __shfl_down(sF, off, 64);
    sS += __shfl_down(sS, off, 64);
    sN += __shfl_down(sN, off, 64);
  }
  __shared__ float vF[4], vS[4];
  __shared__ int   vN[4];
  int lane = tid & 63, wid = tid >> 6;
  if (lane == 0) { vF[wid] = sF; vS[wid] = sS; vN[wid] = sN; }
  __syncthreads();
  if (tid == 0) {
    float f = vF[0] + vF[1] + vF[2] + vF[3];
    float s = vS[0] + vS[1] + vS[2] + vS[3];
    int   n = vN[0] + vN[1] + vN[2] + vN[3];
    float np = (float)(n >= 1 ? n : 1);
    out[0] = f / np + s / (np * 4.f);
  }
}

// ---------------------------------------------------------------- launch
extern "C" void kernel_launch(void* const* d_in, const int* in_sizes, int n_in,
                              void* d_out, int out_size, void* d_ws, size_t ws_size,
                              hipStream_t stream) {
  const float* plocs   = (const float*)d_in[0];   // [B,P,4]
  const float* pscores = (const float*)d_in[1];   // [B,P,80]
  const float* boxes   = (const float*)d_in[2];   // [B,32,4]
  const int*   labels  = (const int*)d_in[3];     // [B,32]
  const float* priors  = (const float*)d_in[4];   // [P,4]
  float* out = (float*)d_out;

  char* w = (char*)d_ws;
  unsigned long long* objbest = (unsigned long long*)w;  // 512 u64    @0
  float* partB   = (float*)(w + 4096);                   // NBLK floats
  float* partS   = (float*)(w + 16384);                  // NBLK floats
  int*   partN   = (int*)(w + 28672);                    // NBLK ints
  float* partC   = (float*)(w + 40960);                  // NBLK floats
  float* rowsumS = (float*)(w + 65536);                  // BP floats (1.44 MB)

  k_bulk<<<NBLK + OBJB, 256, 0, stream>>>(
      (const float4*)pscores, (const float4*)boxes, (const float4*)priors,
      rowsumS, partB, objbest);
  dim3 g(CHUNKS, B);
  k_prep<<<g, 256, 0, stream>>>(
      (const float4*)plocs, pscores, (const float4*)boxes, labels,
      (const float4*)priors, objbest, rowsumS, partS, partN, partC);
  k_final<<<1, 256, 0, stream>>>(partB, partC, partS, partN, out);
}